// Round 6
// baseline (210.351 us; speedup 1.0000x reference)
//
#include <hip/hip_runtime.h>

// FlowNet correlation: out[b, dy*9+dx, y, x] = (1/256) sum_c x1[b,c,y,x] * x2[b,c,y+dy-4,x+dx-4]
// B=4 C=256 H=W=128, 9x9 displacements, zero padding.
//
// Round-10 = round-4 data path EXACTLY + counted-vmem raw barrier (T3/T4):
//   __syncthreads() forces s_waitcnt vmcnt(0) at EVERY chunk barrier -> the
//   chunk-k+1 prefetch is force-drained 64 times (r9 proved issue placement
//   is irrelevant under the drain: zero delta). Fix = lgkmcnt(0)-only barrier:
//     asm s_waitcnt lgkmcnt(0); s_barrier; sched_barrier(0)
//   LDS visibility: writers drain lgkm before barrier (sufficient).
//   Global prefetch loads live in private VGPRs -> legally stay in flight
//   across the barrier; commit uses compiler-inserted COUNTED vmcnt on just
//   those loads. Issue of chunk k+2 now gets ~2 compute phases (~1600+ cy)
//   of cover vs ~900 cy HBM latency.
// Validated-and-kept: 192 thr / 3 waves / tile 16x16 / RSC=48 (conflict-clean)
// / gy=lane>>2 (coalesced) / XCD swizzle / launch_bounds(192,4) (no spill).
// Dead levers (counter-evidence): occupancy r5/r7/r8, issue placement r9.

#define MD 4
constexpr int Bc = 4, Cc = 256, Hc = 128, Wc = 128;
constexpr int TH = 16, TW = 16;
constexpr int NDY = 3;                  // dy per d-group (one per wave)
constexpr int CC = 4;                   // channels per chunk
constexpr int SROWS = TH + NDY - 1;     // 18 staged rows
constexpr int SCOLS = TW + 2 * MD;      // 24 staged cols
constexpr int RSC = 48;                 // padded row stride (dw), 48%32==16 -> clean b128
constexpr int CH_STRIDE = SROWS * RSC;  // 864 dw per channel
constexpr int BUF_DW = CC * CH_STRIDE;  // 3456 dw per buffer
constexpr int NF4 = CC * SROWS * (SCOLS / 4);  // 432 float4 staging slots
constexpr int NTHR = 192;
constexpr int NSLOT = 3;                // ceil(432/192)
constexpr int NK = Cc / CC;             // 64 chunks

// lgkm-only block barrier: LDS writes visible, vmem loads stay outstanding.
#define WAITB() do {                                        \
    asm volatile("s_waitcnt lgkmcnt(0)" ::: "memory");      \
    __builtin_amdgcn_s_barrier();                           \
    __builtin_amdgcn_sched_barrier(0);                      \
} while (0)

__global__ __launch_bounds__(NTHR, 4)
void corr_kernel(const float* __restrict__ x1, const float* __restrict__ x2,
                 float* __restrict__ out)
{
    __shared__ float stg[2 * BUF_DW];   // 27648 B

    const int tid  = threadIdx.x;
    const int w    = tid >> 6;          // wave id = local dy
    const int lane = tid & 63;
    const int gy   = lane >> 2;         // 0..15 tile row
    const int gx   = lane & 3;          // 0..3  col-group (4 px each)

    // ---- XCD-aware swizzle: g-siblings (same tile) differ by +8 in bid -> same XCD ----
    const int bid  = blockIdx.x;
    const int q    = bid / 24;
    const int r    = bid - q * 24;
    const int g    = r >> 3;            // d-group 0..2
    const int t    = q * 8 + (r & 7);   // tile index 0..255
    const int tx = t & 7;
    const int ty = (t >> 3) & 7;
    const int bb = t >> 6;
    const int x0 = tx * TW, y0 = ty * TH;
    const int rowbase = y0 + 3 * g - MD;   // global y of staged row 0

    // ---- hoisted staging slot descriptors (fixed per thread across chunks) ----
    int  s_goff[NSLOT], s_loff[NSLOT];
    bool s_val[NSLOT], s_act[NSLOT];
    #pragma unroll
    for (int s = 0; s < NSLOT; ++s) {
        int idx = tid + s * NTHR;
        bool active = idx < NF4;
        int i2  = active ? idx : 0;
        int cl  = i2 / (SROWS * 6);
        int rem = i2 - cl * (SROWS * 6);
        int rr  = rem / 6;
        int gc  = rem - rr * 6;
        int yy  = rowbase + rr;
        int xx  = x0 - 4 + 4 * gc;          // multiple of 4: float4 all-valid or all-invalid
        s_act[s]  = active;
        s_val[s]  = active && ((unsigned)yy < (unsigned)Hc) && ((unsigned)xx < (unsigned)(Wc - 3));
        s_goff[s] = cl * (Hc * Wc) + yy * Wc + xx;
        s_loff[s] = cl * CH_STRIDE + rr * RSC + 4 * gc;
    }

    const float* x2b = x2 + (size_t)bb * Cc * Hc * Wc;
    const float* x1b = x1 + (((size_t)bb * Cc) * Hc + (y0 + gy)) * Wc + x0 + 4 * gx;

    float acc[9][4];
    #pragma unroll
    for (int dx = 0; dx < 9; ++dx)
        #pragma unroll
        for (int p = 0; p < 4; ++p) acc[dx][p] = 0.f;

    const float4 f40 = make_float4(0.f, 0.f, 0.f, 0.f);
    float4 nf[NSLOT];

    // ---- prologue: stage chunk 0 into buffer 0, then issue chunk-1 loads ----
    #pragma unroll
    for (int s = 0; s < NSLOT; ++s) {
        nf[s] = f40;
        if (s_val[s]) nf[s] = *(const float4*)(x2b + s_goff[s]);
    }
    #pragma unroll
    for (int s = 0; s < NSLOT; ++s)
        if (s_act[s]) *(float4*)(&stg[s_loff[s]]) = nf[s];
    #pragma unroll
    for (int s = 0; s < NSLOT; ++s) {
        nf[s] = f40;
        if (s_val[s]) nf[s] = *(const float4*)(x2b + CC * Hc * Wc + s_goff[s]);
    }

    for (int k = 0; k < NK; ++k) {
        const int pb = k & 1;
        // lgkm-only barrier: buffer k committed & visible; vmem prefetch for
        // chunk k+1 (issued last iteration) stays IN FLIGHT across it.
        WAITB();
        // ---- compute chunk k (x1 loaded inline: L1/L2 hits, no reg pressure) ----
        #pragma unroll
        for (int cl = 0; cl < CC; ++cl) {
            const int c = k * CC + cl;
            const float4 a4 = *(const float4*)(x1b + c * (Hc * Wc));
            const float* rowp = &stg[pb * BUF_DW + cl * CH_STRIDE + (gy + w) * RSC + 4 * gx];
            const float4 q0 = *(const float4*)(rowp);
            const float4 q1 = *(const float4*)(rowp + 4);
            const float4 q2 = *(const float4*)(rowp + 8);
            const float v[12] = {q0.x, q0.y, q0.z, q0.w,
                                 q1.x, q1.y, q1.z, q1.w,
                                 q2.x, q2.y, q2.z, q2.w};
            const float a[4] = {a4.x, a4.y, a4.z, a4.w};
            #pragma unroll
            for (int dx = 0; dx < 9; ++dx)
                #pragma unroll
                for (int p = 0; p < 4; ++p)
                    acc[dx][p] += a[p] * v[dx + p];
        }
        // ---- commit prefetched chunk k+1 (counted vmcnt on nf only; the
        //      buffer being written was last read at iter k-1, upstream of
        //      this iteration's barrier -> WAR-safe) ----
        if (k + 1 < NK) {
            const int lb = ((k + 1) & 1) * BUF_DW;
            #pragma unroll
            for (int s = 0; s < NSLOT; ++s)
                if (s_act[s]) *(float4*)(&stg[lb + s_loff[s]]) = nf[s];
        }
        // ---- issue chunk k+2 loads: these stay outstanding across the next
        //      barrier and land during compute k+1 (~2 phases of cover) ----
        if (k + 2 < NK) {
            const int gof = (k + 2) * CC * Hc * Wc;
            #pragma unroll
            for (int s = 0; s < NSLOT; ++s) {
                nf[s] = f40;
                if (s_val[s]) nf[s] = *(const float4*)(x2b + gof + s_goff[s]);
            }
        }
    }

    // ---- epilogue: scale and store 9 aligned float4 per thread ----
    const float inv = 1.0f / (float)Cc;
    float* ob = out + (((size_t)bb * 81 + (3 * g + w) * 9) * Hc + (y0 + gy)) * Wc + x0 + 4 * gx;
    #pragma unroll
    for (int dx = 0; dx < 9; ++dx) {
        float4 st = make_float4(acc[dx][0] * inv, acc[dx][1] * inv,
                                acc[dx][2] * inv, acc[dx][3] * inv);
        *(float4*)(ob + dx * (Hc * Wc)) = st;
    }
}

extern "C" void kernel_launch(void* const* d_in, const int* in_sizes, int n_in,
                              void* d_out, int out_size, void* d_ws, size_t ws_size,
                              hipStream_t stream) {
    const float* x1 = (const float*)d_in[0];
    const float* x2 = (const float*)d_in[1];
    float* out = (float*)d_out;
    dim3 grid(3 * 8 * 8 * Bc), block(NTHR);   // 768 blocks x 192 threads
    corr_kernel<<<grid, block, 0, stream>>>(x1, x2, out);
}